// Round 3
// baseline (122.022 us; speedup 1.0000x reference)
//
#include <hip/hip_runtime.h>
#include <hip/hip_bf16.h>

#define FDIM 1024
#define KNZ 32
#define NROWS 2048
#define RB 8          // rows per block
#define TPB 1024      // threads per block == FDIM (o = tid)
#define EPSV 1e-6f

static_assert(TPB == FDIM, "o = tid mapping requires TPB == FDIM");
static_assert(NROWS % RB == 0, "rows divide");

// granule swizzle: spreads structured f-sequences across the 8 bank-quads
__device__ __forceinline__ unsigned int swz(unsigned int i) {
  return i ^ ((i >> 3) & 7u);
}

__device__ __forceinline__ unsigned int f2bf(float f) {
  unsigned int u = __float_as_uint(f);
  u += 0x7fffu + ((u >> 16) & 1u);   // RNE
  return u >> 16;
}

__device__ __forceinline__ unsigned int pack2bf(float a, float b) {
  return f2bf(a) | (f2bf(b) << 16);
}

// 4-byte fused entries: low 10 bits = swizzled granule offset, rest = fp32
// weight with its low mantissa bits sacrificed (<=2^-13 relative error).
__global__ void geo_prep(const int* __restrict__ idx,
                         const float* __restrict__ w1,
                         const float* __restrict__ w2,
                         unsigned* __restrict__ pr1, unsigned* __restrict__ pr2) {
  __shared__ int   li[16 * 33];
  __shared__ float l1[16 * 33];
  __shared__ float l2[16 * 33];
  const int t = threadIdx.x;       // 256 threads
  const int o0 = blockIdx.x * 16;  // 16 outputs per block
  #pragma unroll
  for (int e = 0; e < 2; ++e) {
    int j = t + e * 256;           // coalesced global read of [o][k]
    int ol = j >> 5, k = j & 31;
    int g = o0 * KNZ + j;
    li[ol * 33 + k] = idx[g];
    l1[ol * 33 + k] = w1[g];
    l2[ol * 33 + k] = w2[g];
  }
  __syncthreads();
  #pragma unroll
  for (int e = 0; e < 2; ++e) {
    int j = t + e * 256;
    int ol = j & 15, k = j >> 4;   // consecutive t -> consecutive o: coalesced write
    unsigned off = swz((unsigned)li[ol * 33 + k]);
    unsigned wb1 = __float_as_uint(l1[ol * 33 + k]) & 0xFFFFFC00u;
    unsigned wb2 = __float_as_uint(l2[ol * 33 + k]) & 0xFFFFFC00u;
    pr1[k * FDIM + o0 + ol] = wb1 | off;
    pr2[k * FDIM + o0 + ol] = wb2 | off;
  }
}

__device__ __forceinline__ void gather8(unsigned pw, const uint4* lds, float* acc) {
  float w = __uint_as_float(pw & 0xFFFFFC00u) ;
  // NOTE: low bits carry the offset; masking costs 1 VALU but keeps weights exact-ish
  uint4 hv = lds[pw & 1023u];                // ds_read_b128: 8 rows for this (o,k)
  const unsigned int* hd = reinterpret_cast<const unsigned int*>(&hv);
  #pragma unroll
  for (int d = 0; d < 4; ++d) {
    acc[2 * d]     = fmaf(__uint_as_float(hd[d] << 16), w, acc[2 * d]);
    acc[2 * d + 1] = fmaf(__uint_as_float(hd[d] & 0xffff0000u), w, acc[2 * d + 1]);
  }
}

template <bool TR>
__global__ __launch_bounds__(TPB)
void geo_main(const float* __restrict__ x, const float* __restrict__ norm_w,
              const float* __restrict__ b1, const float* __restrict__ amp,
              const float* __restrict__ freq, const float* __restrict__ decay,
              const float* __restrict__ b2, const float* __restrict__ alpha,
              const unsigned* __restrict__ pr1, const unsigned* __restrict__ pr2,
              const int* __restrict__ idx, const float* __restrict__ w1,
              const float* __restrict__ w2, float* __restrict__ out) {
  // granule f holds rows 0..7 of feature f as 8 bf16 (dword d = rows 2d|2d+1)
  __shared__ uint4 h_lds[FDIM];            // 16 KB, holds g*x (rs applied later)
  __shared__ uint4 s_lds[FDIM];            // 16 KB
  __shared__ float red[(TPB / 64) * RB];   // 128 per-wave row partials

  const int tid = threadIdx.x;
  const int lane = tid & 63;
  const int wid = tid >> 6;
  const int r0 = blockIdx.x * RB;
  const int o = tid;

  // ---------- Phase A: load x, params; write g*x (bf16) transposed; wave partials ----------
  float v[RB];
  #pragma unroll
  for (int r = 0; r < RB; ++r)
    v[r] = x[(r0 + r) * FDIM + tid];       // coalesced per row

  const float g   = norm_w[tid];
  const float bb1 = b1[tid], am = amp[tid], fq = freq[tid], dc = decay[tid];
  const float bb2 = b2[tid], al = alpha[0];

  float p[RB];
  #pragma unroll
  for (int r = 0; r < RB; ++r) p[r] = v[r] * v[r];
  #pragma unroll
  for (int s = 1; s < 64; s <<= 1) {
    #pragma unroll
    for (int r = 0; r < RB; ++r) p[r] += __shfl_xor(p[r], s, 64);
  }
  if (lane < RB) red[wid * RB + lane] = p[lane];  // red[w*8 + row]

  {
    uint4 h;
    h.x = pack2bf(g * v[0], g * v[1]);
    h.y = pack2bf(g * v[2], g * v[3]);
    h.z = pack2bf(g * v[4], g * v[5]);
    h.w = pack2bf(g * v[6], g * v[7]);
    h_lds[swz((unsigned)tid)] = h;         // conflict-free under swz
  }

  // prefetch stage-1 group 0 (drains at the barrier -> latency hidden)
  unsigned pw[8];
  if (TR) {
    #pragma unroll
    for (int j = 0; j < 8; ++j) pw[j] = pr1[j * FDIM + o];
  }

  __syncthreads();                          // barrier #1

  // redundant per-wave cross-wave reduce: rs for all 8 rows, no extra barrier
  float rs[RB];
  {
    float a = red[lane] + red[64 + lane];   // w = lane>>3 and 8+(lane>>3), row = lane&7
    a += __shfl_xor(a, 8, 64);
    a += __shfl_xor(a, 16, 64);
    a += __shfl_xor(a, 32, 64);
    float rsl = rsqrtf(a * (1.0f / FDIM) + EPSV);
    #pragma unroll
    for (int r = 0; r < RB; ++r) rs[r] = __shfl(rsl, (lane & ~7) | r, 64);
  }

  // ---------- Stage 1: acc = gather(g*x)·w1 ; z = rs*acc + b1 ; s = sine(z) ----------
  float acc[RB] = {0.f, 0.f, 0.f, 0.f, 0.f, 0.f, 0.f, 0.f};

  if (TR) {
    #pragma unroll
    for (int gk = 0; gk < 4; ++gk) {
      unsigned nx[8];
      if (gk < 3) {
        #pragma unroll
        for (int j = 0; j < 8; ++j) nx[j] = pr1[((gk + 1) * 8 + j) * FDIM + o];
      }
      #pragma unroll
      for (int j = 0; j < 8; ++j) gather8(pw[j], h_lds, acc);
      if (gk < 3) {
        #pragma unroll
        for (int j = 0; j < 8; ++j) pw[j] = nx[j];
      }
    }
  } else {
    #pragma unroll 8
    for (int k = 0; k < KNZ; ++k) {
      unsigned off = swz((unsigned)idx[o * KNZ + k]);
      unsigned wb = __float_as_uint(w1[o * KNZ + k]) & 0xFFFFFC00u;
      gather8(wb | off, h_lds, acc);
    }
  }

  // prefetch stage-2 group 0 (overlaps sine + barrier #2)
  if (TR) {
    #pragma unroll
    for (int j = 0; j < 8; ++j) pw[j] = pr2[j * FDIM + o];
  }

  {
    float s[RB];
    #pragma unroll
    for (int r = 0; r < RB; ++r) {
      float z = fmaf(acc[r], rs[r], bb1);  // rs applied here, off the gather path
      s[r] = am * __sinf(fq * z) * __expf(-dc * z * z);
    }
    uint4 sv;
    sv.x = pack2bf(s[0], s[1]);
    sv.y = pack2bf(s[2], s[3]);
    sv.z = pack2bf(s[4], s[5]);
    sv.w = pack2bf(s[6], s[7]);
    s_lds[swz((unsigned)o)] = sv;          // conflict-free under swz
  }
  __syncthreads();                          // barrier #2

  // ---------- Stage 2: h2 = gather(s)·w2 + b2 ; out = x + alpha*h2 ----------
  #pragma unroll
  for (int r = 0; r < RB; ++r) acc[r] = 0.f;

  if (TR) {
    #pragma unroll
    for (int gk = 0; gk < 4; ++gk) {
      unsigned nx[8];
      if (gk < 3) {
        #pragma unroll
        for (int j = 0; j < 8; ++j) nx[j] = pr2[((gk + 1) * 8 + j) * FDIM + o];
      }
      #pragma unroll
      for (int j = 0; j < 8; ++j) gather8(pw[j], s_lds, acc);
      if (gk < 3) {
        #pragma unroll
        for (int j = 0; j < 8; ++j) pw[j] = nx[j];
      }
    }
  } else {
    #pragma unroll 8
    for (int k = 0; k < KNZ; ++k) {
      unsigned off = swz((unsigned)idx[o * KNZ + k]);
      unsigned wb = __float_as_uint(w2[o * KNZ + k]) & 0xFFFFFC00u;
      gather8(wb | off, s_lds, acc);
    }
  }

  #pragma unroll
  for (int r = 0; r < RB; ++r)
    out[(r0 + r) * FDIM + o] = fmaf(al, acc[r] + bb2, v[r]);  // v[r] = x, in regs
}

extern "C" void kernel_launch(void* const* d_in, const int* in_sizes, int n_in,
                              void* d_out, int out_size, void* d_ws, size_t ws_size,
                              hipStream_t stream) {
  const float* x      = (const float*)d_in[0];
  const int*   idx    = (const int*)d_in[1];
  const float* norm_w = (const float*)d_in[2];
  const float* w1     = (const float*)d_in[3];
  const float* b1     = (const float*)d_in[4];
  const float* amp    = (const float*)d_in[5];
  const float* freq   = (const float*)d_in[6];
  const float* decay  = (const float*)d_in[7];
  const float* w2     = (const float*)d_in[8];
  const float* b2     = (const float*)d_in[9];
  const float* alpha  = (const float*)d_in[10];
  float* out = (float*)d_out;

  const size_t need = 2ull * FDIM * KNZ * sizeof(unsigned);  // 256 KB
  if (ws_size >= need) {
    unsigned* pr1 = (unsigned*)d_ws;
    unsigned* pr2 = pr1 + (size_t)FDIM * KNZ;
    geo_prep<<<FDIM / 16, 256, 0, stream>>>(idx, w1, w2, pr1, pr2);
    geo_main<true><<<NROWS / RB, TPB, 0, stream>>>(
        x, norm_w, b1, amp, freq, decay, b2, alpha, pr1, pr2, idx, w1, w2, out);
  } else {
    geo_main<false><<<NROWS / RB, TPB, 0, stream>>>(
        x, norm_w, b1, amp, freq, decay, b2, alpha, nullptr, nullptr, idx, w1, w2, out);
  }
}

// Round 4
// 87.002 us; speedup vs baseline: 1.4025x; 1.4025x over previous
//
#include <hip/hip_runtime.h>
#include <hip/hip_bf16.h>

#define FDIM 1024
#define KNZ 32
#define NROWS 2048
#define RB 8          // rows per block
#define TPB 1024      // threads per block == FDIM (o = tid)
#define EPSV 1e-6f

static_assert(TPB == FDIM, "o = tid mapping requires TPB == FDIM");
static_assert(NROWS % RB == 0, "rows divide");

// granule swizzle: spreads structured f-sequences across the 8 bank-quads
__device__ __forceinline__ unsigned int swz(unsigned int i) {
  return i ^ ((i >> 3) & 7u);
}

__device__ __forceinline__ unsigned int f2bf(float f) {
  unsigned int u = __float_as_uint(f);
  u += 0x7fffu + ((u >> 16) & 1u);   // RNE
  return u >> 16;
}

__device__ __forceinline__ unsigned int pack2bf(float a, float b) {
  return f2bf(a) | (f2bf(b) << 16);
}

// 4-byte fused entries: low 10 bits = swizzled granule offset, upper bits =
// fp32 weight (low mantissa bits carry the offset; <=2^-13 relative error,
// negligible vs bf16 activations). Used directly as the weight at gather time.
__global__ void geo_prep(const int* __restrict__ idx,
                         const float* __restrict__ w1,
                         const float* __restrict__ w2,
                         unsigned* __restrict__ pr1, unsigned* __restrict__ pr2) {
  __shared__ int   li[16 * 33];
  __shared__ float l1[16 * 33];
  __shared__ float l2[16 * 33];
  const int t = threadIdx.x;       // 256 threads
  const int o0 = blockIdx.x * 16;  // 16 outputs per block
  #pragma unroll
  for (int e = 0; e < 2; ++e) {
    int j = t + e * 256;           // coalesced global read of [o][k]
    int ol = j >> 5, k = j & 31;
    int g = o0 * KNZ + j;
    li[ol * 33 + k] = idx[g];
    l1[ol * 33 + k] = w1[g];
    l2[ol * 33 + k] = w2[g];
  }
  __syncthreads();
  #pragma unroll
  for (int e = 0; e < 2; ++e) {
    int j = t + e * 256;
    int ol = j & 15, k = j >> 4;   // consecutive t -> consecutive o: coalesced write
    unsigned off = swz((unsigned)li[ol * 33 + k]);
    unsigned wb1 = __float_as_uint(l1[ol * 33 + k]) & 0xFFFFFC00u;
    unsigned wb2 = __float_as_uint(l2[ol * 33 + k]) & 0xFFFFFC00u;
    pr1[k * FDIM + o0 + ol] = wb1 | off;
    pr2[k * FDIM + o0 + ol] = wb2 | off;
  }
}

__device__ __forceinline__ void gather8(unsigned pw, const uint4* lds, float* acc) {
  float w = __uint_as_float(pw);             // offset bits = mantissa noise <=2^-13
  uint4 hv = lds[pw & 1023u];                // ds_read_b128: 8 rows for this (o,k)
  const unsigned int* hd = reinterpret_cast<const unsigned int*>(&hv);
  #pragma unroll
  for (int d = 0; d < 4; ++d) {
    acc[2 * d]     = fmaf(__uint_as_float(hd[d] << 16), w, acc[2 * d]);
    acc[2 * d + 1] = fmaf(__uint_as_float(hd[d] & 0xffff0000u), w, acc[2 * d + 1]);
  }
}

template <bool TR>
__global__ __launch_bounds__(TPB, 4)   // 4 waves/SIMD = 1 block/CU -> 128 VGPR budget
void geo_main(const float* __restrict__ x, const float* __restrict__ norm_w,
              const float* __restrict__ b1, const float* __restrict__ amp,
              const float* __restrict__ freq, const float* __restrict__ decay,
              const float* __restrict__ b2, const float* __restrict__ alpha,
              const unsigned* __restrict__ pr1, const unsigned* __restrict__ pr2,
              const int* __restrict__ idx, const float* __restrict__ w1,
              const float* __restrict__ w2, float* __restrict__ out) {
  // granule f holds rows 0..7 of feature f as 8 bf16 (dword d = rows 2d|2d+1)
  __shared__ uint4 h_lds[FDIM];            // 16 KB, holds g*x (rs applied later)
  __shared__ uint4 s_lds[FDIM];            // 16 KB
  __shared__ float red[(TPB / 64) * RB];   // 128 per-wave row partials

  const int tid = threadIdx.x;
  const int lane = tid & 63;
  const int wid = tid >> 6;
  const int r0 = blockIdx.x * RB;
  const int o = tid;

  // ---------- Phase A: load x, params; write g*x (bf16) transposed; wave partials ----------
  float v[RB];
  #pragma unroll
  for (int r = 0; r < RB; ++r)
    v[r] = x[(r0 + r) * FDIM + tid];       // coalesced per row

  const float g   = norm_w[tid];
  const float bb1 = b1[tid], am = amp[tid], fq = freq[tid], dc = decay[tid];
  const float bb2 = b2[tid], al = alpha[0];

  float p[RB];
  #pragma unroll
  for (int r = 0; r < RB; ++r) p[r] = v[r] * v[r];
  #pragma unroll
  for (int s = 1; s < 64; s <<= 1) {
    #pragma unroll
    for (int r = 0; r < RB; ++r) p[r] += __shfl_xor(p[r], s, 64);
  }
  if (lane < RB) red[wid * RB + lane] = p[lane];  // red[w*8 + row]

  {
    uint4 h;
    h.x = pack2bf(g * v[0], g * v[1]);
    h.y = pack2bf(g * v[2], g * v[3]);
    h.z = pack2bf(g * v[4], g * v[5]);
    h.w = pack2bf(g * v[6], g * v[7]);
    h_lds[swz((unsigned)tid)] = h;         // conflict-free under swz
  }

  // prefetch stage-1 group 0 (drains at the barrier -> latency hidden)
  unsigned pw[8];
  if (TR) {
    #pragma unroll
    for (int j = 0; j < 8; ++j) pw[j] = pr1[j * FDIM + o];
  }

  __syncthreads();                          // barrier #1

  // redundant per-wave cross-wave reduce: rs for all 8 rows, no extra barrier
  float rs[RB];
  {
    float a = red[lane] + red[64 + lane];   // w = lane>>3 and 8+(lane>>3), row = lane&7
    a += __shfl_xor(a, 8, 64);
    a += __shfl_xor(a, 16, 64);
    a += __shfl_xor(a, 32, 64);
    float rsl = rsqrtf(a * (1.0f / FDIM) + EPSV);
    #pragma unroll
    for (int r = 0; r < RB; ++r) rs[r] = __shfl(rsl, (lane & ~7) | r, 64);
  }

  // ---------- Stage 1: acc = gather(g*x)·w1 ; z = rs*acc + b1 ; s = sine(z) ----------
  float acc[RB] = {0.f, 0.f, 0.f, 0.f, 0.f, 0.f, 0.f, 0.f};

  if (TR) {
    // consume-then-refill in-place prefetch: 8 live regs, loads land one group ahead
    #pragma unroll
    for (int gk = 0; gk < 4; ++gk) {
      #pragma unroll
      for (int j = 0; j < 8; ++j) {
        unsigned cur = pw[j];
        if (gk < 3) pw[j] = pr1[((gk + 1) * 8 + j) * FDIM + o];
        gather8(cur, h_lds, acc);
      }
    }
  } else {
    #pragma unroll 8
    for (int k = 0; k < KNZ; ++k) {
      unsigned off = swz((unsigned)idx[o * KNZ + k]);
      unsigned wb = __float_as_uint(w1[o * KNZ + k]) & 0xFFFFFC00u;
      gather8(wb | off, h_lds, acc);
    }
  }

  // prefetch stage-2 group 0 (overlaps sine + barrier #2)
  if (TR) {
    #pragma unroll
    for (int j = 0; j < 8; ++j) pw[j] = pr2[j * FDIM + o];
  }

  {
    float s[RB];
    #pragma unroll
    for (int r = 0; r < RB; ++r) {
      float z = fmaf(acc[r], rs[r], bb1);  // rs applied here, off the gather path
      s[r] = am * __sinf(fq * z) * __expf(-dc * z * z);
    }
    uint4 sv;
    sv.x = pack2bf(s[0], s[1]);
    sv.y = pack2bf(s[2], s[3]);
    sv.z = pack2bf(s[4], s[5]);
    sv.w = pack2bf(s[6], s[7]);
    s_lds[swz((unsigned)o)] = sv;          // conflict-free under swz
  }
  __syncthreads();                          // barrier #2

  // ---------- Stage 2: h2 = gather(s)·w2 + b2 ; out = x + alpha*h2 ----------
  #pragma unroll
  for (int r = 0; r < RB; ++r) acc[r] = 0.f;

  if (TR) {
    #pragma unroll
    for (int gk = 0; gk < 4; ++gk) {
      #pragma unroll
      for (int j = 0; j < 8; ++j) {
        unsigned cur = pw[j];
        if (gk < 3) pw[j] = pr2[((gk + 1) * 8 + j) * FDIM + o];
        gather8(cur, s_lds, acc);
      }
    }
  } else {
    #pragma unroll 8
    for (int k = 0; k < KNZ; ++k) {
      unsigned off = swz((unsigned)idx[o * KNZ + k]);
      unsigned wb = __float_as_uint(w2[o * KNZ + k]) & 0xFFFFFC00u;
      gather8(wb | off, s_lds, acc);
    }
  }

  #pragma unroll
  for (int r = 0; r < RB; ++r)
    out[(r0 + r) * FDIM + o] = fmaf(al, acc[r] + bb2, v[r]);  // v[r] = x, in regs
}

extern "C" void kernel_launch(void* const* d_in, const int* in_sizes, int n_in,
                              void* d_out, int out_size, void* d_ws, size_t ws_size,
                              hipStream_t stream) {
  const float* x      = (const float*)d_in[0];
  const int*   idx    = (const int*)d_in[1];
  const float* norm_w = (const float*)d_in[2];
  const float* w1     = (const float*)d_in[3];
  const float* b1     = (const float*)d_in[4];
  const float* amp    = (const float*)d_in[5];
  const float* freq   = (const float*)d_in[6];
  const float* decay  = (const float*)d_in[7];
  const float* w2     = (const float*)d_in[8];
  const float* b2     = (const float*)d_in[9];
  const float* alpha  = (const float*)d_in[10];
  float* out = (float*)d_out;

  const size_t need = 2ull * FDIM * KNZ * sizeof(unsigned);  // 256 KB
  if (ws_size >= need) {
    unsigned* pr1 = (unsigned*)d_ws;
    unsigned* pr2 = pr1 + (size_t)FDIM * KNZ;
    geo_prep<<<FDIM / 16, 256, 0, stream>>>(idx, w1, w2, pr1, pr2);
    geo_main<true><<<NROWS / RB, TPB, 0, stream>>>(
        x, norm_w, b1, amp, freq, decay, b2, alpha, pr1, pr2, idx, w1, w2, out);
  } else {
    geo_main<false><<<NROWS / RB, TPB, 0, stream>>>(
        x, norm_w, b1, amp, freq, decay, b2, alpha, nullptr, nullptr, idx, w1, w2, out);
  }
}

// Round 5
// 25.348 us; speedup vs baseline: 4.8138x; 3.4323x over previous
//
#include <hip/hip_runtime.h>
#include <hip/hip_bf16.h>

#define FDIM 1024
#define KNZ 32
#define NROWS 2048
#define RB 8          // rows per block
#define TPB 1024      // threads per block == FDIM (o = tid)
#define EPSV 1e-6f

static_assert(TPB == FDIM, "o = tid mapping requires TPB == FDIM");
static_assert(NROWS % RB == 0, "rows divide");

// granule swizzle: spreads structured f-sequences across the 8 bank-quads
__device__ __forceinline__ unsigned int swz(unsigned int i) {
  return i ^ ((i >> 3) & 7u);
}

__device__ __forceinline__ unsigned int f2bf(float f) {
  unsigned int u = __float_as_uint(f);
  u += 0x7fffu + ((u >> 16) & 1u);   // RNE
  return u >> 16;
}

__device__ __forceinline__ unsigned int pack2bf(float a, float b) {
  return f2bf(a) | (f2bf(b) << 16);
}

// 4-byte fused entries: low 10 bits = swizzled granule offset, upper bits =
// fp32 weight (low mantissa bits carry the offset; <=2^-13 relative error,
// negligible vs bf16 activations). Used directly as the weight at gather time.
__global__ void geo_prep(const int* __restrict__ idx,
                         const float* __restrict__ w1,
                         const float* __restrict__ w2,
                         unsigned* __restrict__ pr1, unsigned* __restrict__ pr2) {
  __shared__ int   li[16 * 33];
  __shared__ float l1[16 * 33];
  __shared__ float l2[16 * 33];
  const int t = threadIdx.x;       // 256 threads
  const int o0 = blockIdx.x * 16;  // 16 outputs per block
  #pragma unroll
  for (int e = 0; e < 2; ++e) {
    int j = t + e * 256;           // coalesced global read of [o][k]
    int ol = j >> 5, k = j & 31;
    int g = o0 * KNZ + j;
    li[ol * 33 + k] = idx[g];
    l1[ol * 33 + k] = w1[g];
    l2[ol * 33 + k] = w2[g];
  }
  __syncthreads();
  #pragma unroll
  for (int e = 0; e < 2; ++e) {
    int j = t + e * 256;
    int ol = j & 15, k = j >> 4;   // consecutive t -> consecutive o: coalesced write
    unsigned off = swz((unsigned)li[ol * 33 + k]);
    unsigned wb1 = __float_as_uint(l1[ol * 33 + k]) & 0xFFFFFC00u;
    unsigned wb2 = __float_as_uint(l2[ol * 33 + k]) & 0xFFFFFC00u;
    pr1[k * FDIM + o0 + ol] = wb1 | off;
    pr2[k * FDIM + o0 + ol] = wb2 | off;
  }
}

__device__ __forceinline__ void gather8(unsigned pw, const uint4* lds, float* acc) {
  float w = __uint_as_float(pw);             // offset bits = mantissa noise <=2^-13
  uint4 hv = lds[pw & 1023u];                // ds_read_b128: 8 rows for this (o,k)
  const unsigned int* hd = reinterpret_cast<const unsigned int*>(&hv);
  #pragma unroll
  for (int d = 0; d < 4; ++d) {
    acc[2 * d]     = fmaf(__uint_as_float(hd[d] << 16), w, acc[2 * d]);
    acc[2 * d + 1] = fmaf(__uint_as_float(hd[d] & 0xffff0000u), w, acc[2 * d + 1]);
  }
}

template <bool TR>
__global__ __launch_bounds__(TPB, 4)
void geo_main(const float* __restrict__ x, const float* __restrict__ norm_w,
              const float* __restrict__ b1, const float* __restrict__ amp,
              const float* __restrict__ freq, const float* __restrict__ decay,
              const float* __restrict__ b2, const float* __restrict__ alpha,
              const unsigned* __restrict__ pr1, const unsigned* __restrict__ pr2,
              const int* __restrict__ idx, const float* __restrict__ w1,
              const float* __restrict__ w2, float* __restrict__ out) {
  // granule f holds rows 0..7 of feature f as 8 bf16 (dword d = rows 2d|2d+1)
  __shared__ uint4 h_lds[FDIM];            // 16 KB, holds g*x (rs applied later)
  __shared__ uint4 s_lds[FDIM];            // 16 KB
  __shared__ float red[(TPB / 64) * RB];   // 128 per-wave row partials

  const int tid = threadIdx.x;
  const int lane = tid & 63;
  const int wid = tid >> 6;
  const int r0 = blockIdx.x * RB;
  const int o = tid;

  // ---------- Phase A: load x; write g*x (bf16) transposed; wave partials ----------
  float v[RB];
  #pragma unroll
  for (int r = 0; r < RB; ++r)
    v[r] = x[(r0 + r) * FDIM + tid];       // coalesced per row

  const float g = norm_w[tid];

  {
    float p[RB];
    #pragma unroll
    for (int r = 0; r < RB; ++r) p[r] = v[r] * v[r];
    #pragma unroll
    for (int s = 1; s < 64; s <<= 1) {
      #pragma unroll
      for (int r = 0; r < RB; ++r) p[r] += __shfl_xor(p[r], s, 64);
    }
    if (lane < RB) red[wid * RB + lane] = p[lane];  // red[w*8 + row]
  }

  {
    uint4 h;
    h.x = pack2bf(g * v[0], g * v[1]);
    h.y = pack2bf(g * v[2], g * v[3]);
    h.z = pack2bf(g * v[4], g * v[5]);
    h.w = pack2bf(g * v[6], g * v[7]);
    h_lds[swz((unsigned)tid)] = h;         // conflict-free under swz
  }

  __syncthreads();                          // barrier #1

  // redundant per-wave cross-wave reduce; ONE live register (row = lane&7)
  float rsl;
  {
    float a = red[lane] + red[64 + lane];   // red[w*8+row]: w = lane>>3, 8+(lane>>3)
    a += __shfl_xor(a, 8, 64);
    a += __shfl_xor(a, 16, 64);
    a += __shfl_xor(a, 32, 64);
    rsl = rsqrtf(a * (1.0f / FDIM) + EPSV);
  }

  // ---------- Stage 1: acc = gather(g*x)·w1 ----------
  float acc[RB] = {0.f, 0.f, 0.f, 0.f, 0.f, 0.f, 0.f, 0.f};

  if (TR) {
    #pragma unroll 8
    for (int k = 0; k < KNZ; ++k)
      gather8(pr1[k * FDIM + o], h_lds, acc);   // table load inside loop: no stash
  } else {
    #pragma unroll 8
    for (int k = 0; k < KNZ; ++k) {
      unsigned off = swz((unsigned)idx[o * KNZ + k]);
      unsigned wb = __float_as_uint(w1[o * KNZ + k]) & 0xFFFFFC00u;
      gather8(wb | off, h_lds, acc);
    }
  }

  // epilogue 1: z = rs*acc + b1 ; s = amp*sin(freq z)*exp(-decay z^2)
  {
    const float bb1 = b1[o], am = amp[o], fq = freq[o], dc = decay[o];
    float s[RB];
    #pragma unroll
    for (int r = 0; r < RB; ++r) {
      float rsr = __shfl(rsl, (lane & ~7) | r, 64);  // broadcast at use, not held
      float z = fmaf(acc[r], rsr, bb1);
      s[r] = am * __sinf(fq * z) * __expf(-dc * z * z);
    }
    uint4 sv;
    sv.x = pack2bf(s[0], s[1]);
    sv.y = pack2bf(s[2], s[3]);
    sv.z = pack2bf(s[4], s[5]);
    sv.w = pack2bf(s[6], s[7]);
    s_lds[swz((unsigned)o)] = sv;          // conflict-free under swz
  }
  __syncthreads();                          // barrier #2

  // ---------- Stage 2: h2 = gather(s)·w2 + b2 ; out = x + alpha*h2 ----------
  #pragma unroll
  for (int r = 0; r < RB; ++r) acc[r] = 0.f;

  if (TR) {
    #pragma unroll 8
    for (int k = 0; k < KNZ; ++k)
      gather8(pr2[k * FDIM + o], s_lds, acc);
  } else {
    #pragma unroll 8
    for (int k = 0; k < KNZ; ++k) {
      unsigned off = swz((unsigned)idx[o * KNZ + k]);
      unsigned wb = __float_as_uint(w2[o * KNZ + k]) & 0xFFFFFC00u;
      gather8(wb | off, s_lds, acc);
    }
  }

  {
    const float bb2 = b2[o];
    const float al = alpha[0];
    #pragma unroll
    for (int r = 0; r < RB; ++r)
      out[(r0 + r) * FDIM + o] = fmaf(al, acc[r] + bb2, v[r]);  // v[r] = x, in regs
  }
}

extern "C" void kernel_launch(void* const* d_in, const int* in_sizes, int n_in,
                              void* d_out, int out_size, void* d_ws, size_t ws_size,
                              hipStream_t stream) {
  const float* x      = (const float*)d_in[0];
  const int*   idx    = (const int*)d_in[1];
  const float* norm_w = (const float*)d_in[2];
  const float* w1     = (const float*)d_in[3];
  const float* b1     = (const float*)d_in[4];
  const float* amp    = (const float*)d_in[5];
  const float* freq   = (const float*)d_in[6];
  const float* decay  = (const float*)d_in[7];
  const float* w2     = (const float*)d_in[8];
  const float* b2     = (const float*)d_in[9];
  const float* alpha  = (const float*)d_in[10];
  float* out = (float*)d_out;

  const size_t need = 2ull * FDIM * KNZ * sizeof(unsigned);  // 256 KB
  if (ws_size >= need) {
    unsigned* pr1 = (unsigned*)d_ws;
    unsigned* pr2 = pr1 + (size_t)FDIM * KNZ;
    geo_prep<<<FDIM / 16, 256, 0, stream>>>(idx, w1, w2, pr1, pr2);
    geo_main<true><<<NROWS / RB, TPB, 0, stream>>>(
        x, norm_w, b1, amp, freq, decay, b2, alpha, pr1, pr2, idx, w1, w2, out);
  } else {
    geo_main<false><<<NROWS / RB, TPB, 0, stream>>>(
        x, norm_w, b1, amp, freq, decay, b2, alpha, nullptr, nullptr, idx, w1, w2, out);
  }
}

// Round 6
// 21.886 us; speedup vs baseline: 5.5754x; 1.1582x over previous
//
#include <hip/hip_runtime.h>
#include <hip/hip_bf16.h>

#define FDIM 1024
#define KNZ 32
#define NROWS 2048
#define RB 8          // rows per block
#define TPB 1024      // threads per block == FDIM (o = tid)
#define EPSV 1e-6f

static_assert(TPB == FDIM, "o = tid mapping requires TPB == FDIM");
static_assert(NROWS % RB == 0, "rows divide");

// granule swizzle: spreads structured f-sequences across the 8 bank-quads
__device__ __forceinline__ unsigned int swz(unsigned int i) {
  return i ^ ((i >> 3) & 7u);
}

__device__ __forceinline__ unsigned int f2bf(float f) {
  unsigned int u = __float_as_uint(f);
  u += 0x7fffu + ((u >> 16) & 1u);   // RNE
  return u >> 16;
}

__device__ __forceinline__ unsigned int pack2bf(float a, float b) {
  return f2bf(a) | (f2bf(b) << 16);
}

// 4-byte fused entries: low 10 bits = swizzled granule offset, upper bits =
// fp32 weight (low mantissa bits carry the offset; <=2^-13 relative error,
// negligible vs bf16 activations). Used directly as the weight at gather time.
__global__ void geo_prep(const int* __restrict__ idx,
                         const float* __restrict__ w1,
                         const float* __restrict__ w2,
                         unsigned* __restrict__ pr1, unsigned* __restrict__ pr2) {
  __shared__ int   li[16 * 33];
  __shared__ float l1[16 * 33];
  __shared__ float l2[16 * 33];
  const int t = threadIdx.x;       // 256 threads
  const int o0 = blockIdx.x * 16;  // 16 outputs per block
  #pragma unroll
  for (int e = 0; e < 2; ++e) {
    int j = t + e * 256;           // coalesced global read of [o][k]
    int ol = j >> 5, k = j & 31;
    int g = o0 * KNZ + j;
    li[ol * 33 + k] = idx[g];
    l1[ol * 33 + k] = w1[g];
    l2[ol * 33 + k] = w2[g];
  }
  __syncthreads();
  #pragma unroll
  for (int e = 0; e < 2; ++e) {
    int j = t + e * 256;
    int ol = j & 15, k = j >> 4;   // consecutive t -> consecutive o: coalesced write
    unsigned off = swz((unsigned)li[ol * 33 + k]);
    unsigned wb1 = __float_as_uint(l1[ol * 33 + k]) & 0xFFFFFC00u;
    unsigned wb2 = __float_as_uint(l2[ol * 33 + k]) & 0xFFFFFC00u;
    pr1[k * FDIM + o0 + ol] = wb1 | off;
    pr2[k * FDIM + o0 + ol] = wb2 | off;
  }
}

__device__ __forceinline__ void gather8(unsigned pw, const uint4* lds, float* acc) {
  float w = __uint_as_float(pw);             // offset bits = mantissa noise <=2^-13
  uint4 hv = lds[pw & 1023u];                // ds_read_b128: 8 rows for this (o,k)
  const unsigned int* hd = reinterpret_cast<const unsigned int*>(&hv);
  #pragma unroll
  for (int d = 0; d < 4; ++d) {
    acc[2 * d]     = fmaf(__uint_as_float(hd[d] << 16), w, acc[2 * d]);
    acc[2 * d + 1] = fmaf(__uint_as_float(hd[d] & 0xffff0000u), w, acc[2 * d + 1]);
  }
}

template <bool TR>
__global__ __launch_bounds__(TPB, 4)
void geo_main(const float* __restrict__ x, const float* __restrict__ norm_w,
              const float* __restrict__ b1, const float* __restrict__ amp,
              const float* __restrict__ freq, const float* __restrict__ decay,
              const float* __restrict__ b2, const float* __restrict__ alpha,
              const unsigned* __restrict__ pr1, const unsigned* __restrict__ pr2,
              const int* __restrict__ idx, const float* __restrict__ w1,
              const float* __restrict__ w2, float* __restrict__ out) {
  // granule f holds rows 0..7 of feature f as 8 bf16 (dword d = rows 2d|2d+1)
  __shared__ uint4 h_lds[FDIM];            // 16 KB, holds g*x (rs applied later)
  __shared__ uint4 s_lds[FDIM];            // 16 KB
  __shared__ float red[(TPB / 64) * RB];   // 128 per-wave row partials
  __shared__ float rs_sh[RB];              // final rs per row

  const int tid = threadIdx.x;
  const int lane = tid & 63;
  const int wid = tid >> 6;
  const int r0 = blockIdx.x * RB;
  const int o = tid;

  // ---------- Phase A: load x; write g*x (bf16) transposed; wave partials ----------
  float v[RB];
  #pragma unroll
  for (int r = 0; r < RB; ++r)
    v[r] = x[(r0 + r) * FDIM + tid];       // coalesced per row

  const float g = norm_w[tid];

  // log-row-halving reduce: 17 shfl instead of 48.
  {
    float p[RB];
    #pragma unroll
    for (int r = 0; r < RB; ++r) p[r] = v[r] * v[r];
    // mask 4: keep rows 0-3 on (lane&4)==0, rows 4-7 (in slots 0-3) on (lane&4)!=0
    #pragma unroll
    for (int r = 0; r < 4; ++r) {
      float up = __shfl_xor(p[r + 4], 4, 64);  // partner's p[r+4]
      float dn = __shfl_xor(p[r], 4, 64);      // partner's p[r]
      p[r] = (lane & 4) ? (p[r + 4] + up) : (p[r] + dn);
    }
    // mask 2
    #pragma unroll
    for (int r = 0; r < 2; ++r) {
      float up = __shfl_xor(p[r + 2], 2, 64);
      float dn = __shfl_xor(p[r], 2, 64);
      p[r] = (lane & 2) ? (p[r + 2] + up) : (p[r] + dn);
    }
    // mask 1
    {
      float up = __shfl_xor(p[1], 1, 64);
      float dn = __shfl_xor(p[0], 1, 64);
      p[0] = (lane & 1) ? (p[1] + up) : (p[0] + dn);
    }
    // now lane l holds its 8-lane-group partial of row (l&7); fold the 8 groups
    p[0] += __shfl_xor(p[0], 8, 64);
    p[0] += __shfl_xor(p[0], 16, 64);
    p[0] += __shfl_xor(p[0], 32, 64);
    if (lane < RB) red[wid * RB + lane] = p[0];  // red[w*8 + row]
  }

  {
    uint4 h;
    h.x = pack2bf(g * v[0], g * v[1]);
    h.y = pack2bf(g * v[2], g * v[3]);
    h.z = pack2bf(g * v[4], g * v[5]);
    h.w = pack2bf(g * v[6], g * v[7]);
    h_lds[swz((unsigned)tid)] = h;         // conflict-free under swz
  }

  __syncthreads();                          // barrier #1

  // every wave redundantly folds the 16 wave-partials and writes the SAME
  // rs_sh[0..7]; own-wave program order guarantees visibility at the epilogue.
  {
    float a = red[lane] + red[64 + lane];   // red[w*8+row]: w = lane>>3, 8+(lane>>3)
    a += __shfl_xor(a, 8, 64);
    a += __shfl_xor(a, 16, 64);
    a += __shfl_xor(a, 32, 64);
    if (lane < RB) rs_sh[lane] = rsqrtf(a * (1.0f / FDIM) + EPSV);
  }

  // ---------- Stage 1: acc = gather(g*x)·w1 ----------
  float acc[RB] = {0.f, 0.f, 0.f, 0.f, 0.f, 0.f, 0.f, 0.f};

  if (TR) {
    #pragma unroll
    for (int gk = 0; gk < 4; ++gk) {
      unsigned u[8];                        // transient: 8 loads in flight
      #pragma unroll
      for (int j = 0; j < 8; ++j) u[j] = pr1[(gk * 8 + j) * FDIM + o];
      #pragma unroll
      for (int j = 0; j < 8; ++j) gather8(u[j], h_lds, acc);
    }
  } else {
    #pragma unroll 8
    for (int k = 0; k < KNZ; ++k) {
      unsigned off = swz((unsigned)idx[o * KNZ + k]);
      unsigned wb = __float_as_uint(w1[o * KNZ + k]) & 0xFFFFFC00u;
      gather8(wb | off, h_lds, acc);
    }
  }

  // epilogue 1: z = rs*acc + b1 ; s = amp*sin(freq z)*exp(-decay z^2)
  {
    const float bb1 = b1[o], am = amp[o], fq = freq[o], dc = decay[o];
    const float4 ra = *reinterpret_cast<const float4*>(&rs_sh[0]);  // broadcast b128
    const float4 rb = *reinterpret_cast<const float4*>(&rs_sh[4]);
    const float rsv[RB] = {ra.x, ra.y, ra.z, ra.w, rb.x, rb.y, rb.z, rb.w};
    float s[RB];
    #pragma unroll
    for (int r = 0; r < RB; ++r) {
      float z = fmaf(acc[r], rsv[r], bb1);
      s[r] = am * __sinf(fq * z) * __expf(-dc * z * z);
    }
    uint4 sv;
    sv.x = pack2bf(s[0], s[1]);
    sv.y = pack2bf(s[2], s[3]);
    sv.z = pack2bf(s[4], s[5]);
    sv.w = pack2bf(s[6], s[7]);
    s_lds[swz((unsigned)o)] = sv;          // conflict-free under swz
  }
  __syncthreads();                          // barrier #2

  // ---------- Stage 2: h2 = gather(s)·w2 + b2 ; out = x + alpha*h2 ----------
  #pragma unroll
  for (int r = 0; r < RB; ++r) acc[r] = 0.f;

  if (TR) {
    #pragma unroll
    for (int gk = 0; gk < 4; ++gk) {
      unsigned u[8];
      #pragma unroll
      for (int j = 0; j < 8; ++j) u[j] = pr2[(gk * 8 + j) * FDIM + o];
      #pragma unroll
      for (int j = 0; j < 8; ++j) gather8(u[j], s_lds, acc);
    }
  } else {
    #pragma unroll 8
    for (int k = 0; k < KNZ; ++k) {
      unsigned off = swz((unsigned)idx[o * KNZ + k]);
      unsigned wb = __float_as_uint(w2[o * KNZ + k]) & 0xFFFFFC00u;
      gather8(wb | off, s_lds, acc);
    }
  }

  {
    const float bb2 = b2[o];
    const float al = alpha[0];
    #pragma unroll
    for (int r = 0; r < RB; ++r)
      out[(r0 + r) * FDIM + o] = fmaf(al, acc[r] + bb2, v[r]);  // v[r] = x, in regs
  }
}

extern "C" void kernel_launch(void* const* d_in, const int* in_sizes, int n_in,
                              void* d_out, int out_size, void* d_ws, size_t ws_size,
                              hipStream_t stream) {
  const float* x      = (const float*)d_in[0];
  const int*   idx    = (const int*)d_in[1];
  const float* norm_w = (const float*)d_in[2];
  const float* w1     = (const float*)d_in[3];
  const float* b1     = (const float*)d_in[4];
  const float* amp    = (const float*)d_in[5];
  const float* freq   = (const float*)d_in[6];
  const float* decay  = (const float*)d_in[7];
  const float* w2     = (const float*)d_in[8];
  const float* b2     = (const float*)d_in[9];
  const float* alpha  = (const float*)d_in[10];
  float* out = (float*)d_out;

  const size_t need = 2ull * FDIM * KNZ * sizeof(unsigned);  // 256 KB
  if (ws_size >= need) {
    unsigned* pr1 = (unsigned*)d_ws;
    unsigned* pr2 = pr1 + (size_t)FDIM * KNZ;
    geo_prep<<<FDIM / 16, 256, 0, stream>>>(idx, w1, w2, pr1, pr2);
    geo_main<true><<<NROWS / RB, TPB, 0, stream>>>(
        x, norm_w, b1, amp, freq, decay, b2, alpha, pr1, pr2, idx, w1, w2, out);
  } else {
    geo_main<false><<<NROWS / RB, TPB, 0, stream>>>(
        x, norm_w, b1, amp, freq, decay, b2, alpha, nullptr, nullptr, idx, w1, w2, out);
  }
}